// Round 10
// baseline (26581.570 us; speedup 1.0000x reference)
//
#include <hip/hip_runtime.h>
#include <math.h>

#define NSTACKC 4
#define FD 8
#define HD 64
#define KD 10
#define MD 29
#define TBF 4.0f
#define NTHR 256     // 4-wave workgroups: only shape with proven spill-free
                     // allocation (R1/R9). 512-thr always pinned 64-92 VGPR
                     // and spilled h2[64] (R2-R8).
#define RPB 256      // rows per block (4 waves x 64 lanes)
#define H1CH 16      // h1 chunk size (h2[64] is the long-lived accumulator)
#define W2P 32       // padded W2 row stride in LDS (29 -> 32, 16B-aligned rows)

__device__ __forceinline__ float splus(float v) {
    // softplus: log1p(exp(v)), stable for large v
    return (v > 20.0f) ? v : log1pf(__expf(v));
}

// One launch per stack (4 total). Block = (feature fi, 256-row tile): stages
// this (s,fi)'s 26 KB of weights into LDS once; weight reads are then
// same-address broadcasts (conflict-free) through the deep VGPR file instead
// of s_load chains through the ~102-SGPR file (R9 diagnosis: 27% VALUBusy =
// s_load latency with ~2 dwordx16 in flight). Reversal between stacks is
// folded into the read (rev flag); writes always direct.
__global__
__attribute__((amdgpu_flat_work_group_size(NTHR, NTHR)))
void nsf_stack_kernel(
    const float* __restrict__ Xin,
    float* __restrict__ Xout,
    const float* __restrict__ W0,
    const float* __restrict__ B0,
    const float* __restrict__ W1,
    const float* __restrict__ B1,
    const float* __restrict__ W2,
    const float* __restrict__ B2,
    int s, int rev, int Bn)
{
    __shared__ float lw0[FD * HD];    //  2 KB  [f][h]
    __shared__ float lw1[HD * HD];    // 16 KB  [hh][oo]
    __shared__ float lw2[HD * W2P];   //  8 KB  [hh][m] padded
    __shared__ float lb0[HD];
    __shared__ float lb1[HD];
    __shared__ float lb2[W2P];

    const int t  = threadIdx.x;
    const int fi = blockIdx.y;        // feature for this block (uniform, SGPR)

    // ---- stage this (stack, feature)'s weights into LDS (coalesced) ----
    {
        const size_t sf = (size_t)(s * FD + fi);
        const float* g0 = W0 + sf * FD * HD;
        for (int idx = t; idx < FD * HD; idx += NTHR) lw0[idx] = g0[idx];
        const float* g1 = W1 + sf * HD * HD;
        for (int idx = t; idx < HD * HD; idx += NTHR) lw1[idx] = g1[idx];
        const float* g2 = W2 + sf * HD * MD;
        for (int idx = t; idx < HD * MD; idx += NTHR) {
            int hh = idx / MD;
            lw2[hh * W2P + (idx - hh * MD)] = g2[idx];
        }
        if (t < HD) {
            lb0[t] = B0[sf * HD + t];
            lb1[t] = B1[sf * HD + t];
        }
        if (t < MD) lb2[t] = B2[sf * MD + t];
    }
    __syncthreads();

    const size_t row = (size_t)blockIdx.x * RPB + t;   // t in [0,256): 4 waves x 64 rows
    const bool valid = row < (size_t)Bn;

    // ---- load this row's x (reversal of previous stack's y baked in) ----
    float x[FD];
    if (valid) {
        const float4* xp = (const float4*)(Xin + row * FD);
        float4 a = xp[0], b = xp[1];
        if (rev) {
            x[0] = b.w; x[1] = b.z; x[2] = b.y; x[3] = b.x;
            x[4] = a.w; x[5] = a.z; x[6] = a.y; x[7] = a.x;
        } else {
            x[0] = a.x; x[1] = a.y; x[2] = a.z; x[3] = a.w;
            x[4] = b.x; x[5] = b.y; x[6] = b.z; x[7] = b.w;
        }
    } else {
        #pragma unroll
        for (int f = 0; f < FD; ++f) x[f] = 0.0f;
    }
    float xi = 0.0f;
    #pragma unroll
    for (int f = 0; f < FD; ++f) if (fi == f) xi = x[f];  // uniform selects

    // ---- layers 1+2 fused: h2[64] accumulates; h1 in chunks of 16 ----
    float h2[HD];
    #pragma unroll
    for (int oo = 0; oo < HD; ++oo) h2[oo] = lb1[oo];

    #pragma unroll
    for (int c = 0; c < HD / H1CH; ++c) {
        float h1c[H1CH];
        #pragma unroll
        for (int j = 0; j < H1CH; ++j) h1c[j] = lb0[c * H1CH + j];
        #pragma unroll
        for (int f = 0; f < FD; ++f) {
            if (f <= fi) {  // uniform branch (fi is SGPR), skips whole FMA block
                float xf = x[f];
                const float* wr = &lw0[f * HD + c * H1CH];
                #pragma unroll
                for (int j = 0; j < H1CH; ++j)
                    h1c[j] = fmaf(xf, wr[j], h1c[j]);
            }
        }
        #pragma unroll
        for (int j = 0; j < H1CH; ++j) {
            float hv = fmaxf(h1c[j], 0.0f);
            const float* wr = &lw1[(c * H1CH + j) * HD];
            #pragma unroll
            for (int oo = 0; oo < HD; ++oo)
                h2[oo] = fmaf(hv, wr[oo], h2[oo]);
        }
    }

    // ---- layer 3: 64 -> 29 ----
    float p[MD];
    #pragma unroll
    for (int m = 0; m < MD; ++m) p[m] = lb2[m];
    #pragma unroll
    for (int hh = 0; hh < HD; ++hh) {
        float hv = fmaxf(h2[hh], 0.0f);
        const float* wr = &lw2[hh * W2P];
        #pragma unroll
        for (int m = 0; m < MD; ++m)
            p[m] = fmaf(hv, wr[m], p[m]);
    }

    // ---- rational-quadratic spline on feature fi ----
    // widths
    float mw = p[0];
    #pragma unroll
    for (int k = 1; k < KD; ++k) mw = fmaxf(mw, p[k]);
    float ew[KD];
    float sw = 0.0f;
    #pragma unroll
    for (int k = 0; k < KD; ++k) { ew[k] = __expf(p[k] - mw); sw += ew[k]; }
    float invw = 1.0f / sw;
    float cw[KD + 1];
    cw[0] = -TBF;
    {
        float acc = 0.0f;
        #pragma unroll
        for (int k = 0; k < KD; ++k) {
            float wk = 0.001f + (1.0f - 0.001f * KD) * ew[k] * invw;
            acc += wk;
            cw[k + 1] = 2.0f * TBF * acc - TBF;
        }
    }
    cw[KD] = TBF;

    // heights
    float mh = p[KD];
    #pragma unroll
    for (int k = 1; k < KD; ++k) mh = fmaxf(mh, p[KD + k]);
    float eh[KD];
    float sh = 0.0f;
    #pragma unroll
    for (int k = 0; k < KD; ++k) { eh[k] = __expf(p[KD + k] - mh); sh += eh[k]; }
    float invh = 1.0f / sh;
    float ch[KD + 1];
    ch[0] = -TBF;
    {
        float acc = 0.0f;
        #pragma unroll
        for (int k = 0; k < KD; ++k) {
            float hk = 0.001f + (1.0f - 0.001f * KD) * eh[k] * invh;
            acc += hk;
            ch[k + 1] = 2.0f * TBF * acc - TBF;
        }
    }
    ch[KD] = TBF;

    // derivatives: d[0]=d[10]=MIN_D+softplus(const)==1.0 exactly
    float d[KD + 1];
    d[0] = 1.0f;
    d[KD] = 1.0f;
    #pragma unroll
    for (int k = 1; k < KD; ++k) d[k] = 0.001f + splus(p[2 * KD + (k - 1)]);

    float xc = fminf(fmaxf(xi, -TBF), TBF);

    // bin select: monotone cndmask chain
    float w_b  = cw[1] - cw[0];
    float cw_b = cw[0];
    float h_b  = ch[1] - ch[0];
    float ch_b = ch[0];
    float d_b  = d[0];
    float d_p1 = d[1];
    #pragma unroll
    for (int k = 1; k < KD; ++k) {
        bool c = xc >= cw[k];
        w_b  = c ? (cw[k + 1] - cw[k]) : w_b;
        cw_b = c ? cw[k] : cw_b;
        h_b  = c ? (ch[k + 1] - ch[k]) : h_b;
        ch_b = c ? ch[k] : ch_b;
        d_b  = c ? d[k] : d_b;
        d_p1 = c ? d[k + 1] : d_p1;
    }

    float theta = (xc - cw_b) / w_b;
    float t1m   = theta * (1.0f - theta);
    float delta = h_b / w_b;
    float num   = h_b * (delta * theta * theta + d_b * t1m);
    float den   = delta + (d_b + d_p1 - 2.0f * delta) * t1m;
    float yv    = ch_b + num / den;
    bool inside = (xi >= -TBF) && (xi <= TBF);
    float y = inside ? yv : xi;

    // ---- write y (always direct; next launch applies reversal on read) ----
    if (valid) Xout[row * FD + fi] = y;
}

extern "C" void kernel_launch(void* const* d_in, const int* in_sizes, int n_in,
                              void* d_out, int out_size, void* d_ws, size_t ws_size,
                              hipStream_t stream) {
    const float* X  = (const float*)d_in[0];
    const float* W0 = (const float*)d_in[1];
    const float* B0 = (const float*)d_in[2];
    const float* W1 = (const float*)d_in[3];
    const float* B1 = (const float*)d_in[4];
    const float* W2 = (const float*)d_in[5];
    const float* B2 = (const float*)d_in[6];
    float* OUT = (float*)d_out;
    float* WS  = (float*)d_ws;   // ping buffer (needs Bn*FD*4 = 2 MB of scratch)

    int Bn = in_sizes[0] / FD;
    dim3 grid((Bn + RPB - 1) / RPB, FD);
    dim3 block(NTHR);

    // stack 0: X -> WS   (read direct)
    hipLaunchKernelGGL(nsf_stack_kernel, grid, block, 0, stream,
                       X, WS, W0, B0, W1, B1, W2, B2, 0, 0, Bn);
    // stack 1: WS -> OUT (read reversed)
    hipLaunchKernelGGL(nsf_stack_kernel, grid, block, 0, stream,
                       WS, OUT, W0, B0, W1, B1, W2, B2, 1, 1, Bn);
    // stack 2: OUT -> WS (read reversed)
    hipLaunchKernelGGL(nsf_stack_kernel, grid, block, 0, stream,
                       OUT, WS, W0, B0, W1, B1, W2, B2, 2, 1, Bn);
    // stack 3: WS -> OUT (read reversed)
    hipLaunchKernelGGL(nsf_stack_kernel, grid, block, 0, stream,
                       WS, OUT, W0, B0, W1, B1, W2, B2, 3, 1, Bn);
}